// Round 13
// baseline (385.025 us; speedup 1.0000x reference)
//
#include <hip/hip_runtime.h>
#include <hip/hip_bf16.h>
#include <hip/hip_cooperative_groups.h>

namespace cg = cooperative_groups;

// Problem constants
#define NB  2      // batch
#define CC  256    // channels
#define NHD 8      // heads
#define HD  32     // head dim
#define NT  4096   // tokens = H*W

typedef __bf16 bf16x8 __attribute__((ext_vector_type(8)));
typedef bf16x8 bf16x8_ma __attribute__((may_alias));
typedef float  f32x4  __attribute__((ext_vector_type(4)));

static __device__ __forceinline__ f32x4 zero4() {
    f32x4 z = {0.f, 0.f, 0.f, 0.f}; return z;
}

// ---------------------------------------------------------------------------
// ROUND 13: OUTPUT IS FLOAT32. The harness assert label "(bf16, ...)" is a
// hardcoded literal; the read path follows the reference's output dtype = f32.
// Writing bf16 into a f32-read buffer pairs our halfwords into f32 slots
// (actual[j] ~ out[2j+1]) -- which quantitatively reproduces EVERY round's
// absmax: R0 4.9375, R8 6.86, R5/6/7 6.9375, R2/3 6.921875, R9-12 band.
// Pipeline (all pieces cross-validated in R2/R3/R5/R6):
//   prep (f32->bf16) -> MFMA qkv -> MFMA flash attn (ao bf16 in d_out upper
//   half) -> cooperative in-place proj + residual, f32 math, F32 STORES.
// ws use: 16.4 MB (R5==R6 bitwise proved this region safe).
// ---------------------------------------------------------------------------

// ---------------------------------------------------------------------------
// Kernel 0: w_qkv f32 -> bf16.  n = 196608, grid 768 x 256.
// ---------------------------------------------------------------------------
__global__ __launch_bounds__(256) void convw_k(const float* __restrict__ src,
                                               __bf16* __restrict__ dst, int n) {
    const int i = blockIdx.x * 256 + threadIdx.x;
    if (i < n) dst[i] = (__bf16)src[i];
}

// ---------------------------------------------------------------------------
// Kernel 1: transpose+convert x f32 [b][c][n] -> xt bf16 [b][n][c].
// thread <-> channel c; each thread reads one full 64B line (16 consecutive n).
// grid (256, 2) x 256.
// ---------------------------------------------------------------------------
__global__ __launch_bounds__(256) void transpose_k(const float* __restrict__ x,
                                                   __bf16* __restrict__ xt) {
    const int c  = threadIdx.x;
    const int b  = blockIdx.y;
    const int n0 = blockIdx.x * 16;
    const float* xp = x  + ((size_t)(b * CC + c)) * NT + n0;
    __bf16*      op = xt + ((size_t)(b * NT + n0)) * CC + c;
#pragma unroll
    for (int i = 0; i < 16; ++i) op[i * CC] = (__bf16)xp[i];
}

// ---------------------------------------------------------------------------
// Kernel 2: QKV GEMM (MFMA, R2-validated).  D[m=o][n=tok] = sum_c W[o][c]*Xt[tok][c]
// Epilogue: qt/kt token-major [bh][n][32] (q scaled 1/sqrt(32)), vv [bh][32][n].
// grid (NT/64, 768/64, NB), block 256.
// ---------------------------------------------------------------------------
__global__ __launch_bounds__(256) void qkv_k(const __bf16* __restrict__ wqkv,
                                             const __bf16* __restrict__ xt,
                                             __bf16* __restrict__ qt,
                                             __bf16* __restrict__ kt,
                                             __bf16* __restrict__ vv) {
    const int lane = threadIdx.x & 63, wv = threadIdx.x >> 6;
    const int g = lane >> 4, c16 = lane & 15;
    const int b    = blockIdx.z;
    const int o0   = blockIdx.y * 64 + wv * 16;
    const int tok0 = blockIdx.x * 64;

    const __bf16* arow = wqkv + (size_t)(o0 + c16) * CC + g * 8;
    const __bf16* brow = xt + ((size_t)(b * NT + tok0 + c16)) * CC + g * 8;

    f32x4 acc[4];
#pragma unroll
    for (int i = 0; i < 4; ++i) acc[i] = zero4();

#pragma unroll
    for (int k0 = 0; k0 < CC; k0 += 32) {
        bf16x8 a = *(const bf16x8_ma*)(arow + k0);
#pragma unroll
        for (int js = 0; js < 4; ++js) {
            bf16x8 bb = *(const bf16x8_ma*)(brow + (size_t)js * 16 * CC + k0);
            acc[js] = __builtin_amdgcn_mfma_f32_16x16x32_bf16(a, bb, acc[js], 0, 0, 0);
        }
    }

#pragma unroll
    for (int js = 0; js < 4; ++js) {
        const int tok = tok0 + js * 16 + c16;
#pragma unroll
        for (int r = 0; r < 4; ++r) {
            const int o   = o0 + g * 4 + r;
            const float v = acc[js][r];
            const int reg = o >> 8;        // 0=q, 1=k, 2=v (wave-uniform)
            const int oo  = o & 255;
            const int h = oo >> 5, dd = oo & 31;
            const size_t bh = (size_t)(b * NHD + h);
            if (reg == 0)      qt[(bh * NT + tok) * HD + dd] = (__bf16)(v * 0.17677669529663687f);
            else if (reg == 1) kt[(bh * NT + tok) * HD + dd] = (__bf16)v;
            else               vv[(bh * HD + dd) * NT + tok] = (__bf16)v;
        }
    }
}

// ---------------------------------------------------------------------------
// Kernel 3: MFMA flash attention (R2/R3 cross-validated).
// block = (b,h) x 64-query tile; wave owns 16 rows; d=32 = one MFMA K.
// P round-trips per-wave-private LDS. ao -> [b][t][c] (bf16).
// grid (NT/64, NB*NHD), block 256.
// ---------------------------------------------------------------------------
__global__ __launch_bounds__(256) void attn_k(const __bf16* __restrict__ qt,
                                              const __bf16* __restrict__ kt,
                                              const __bf16* __restrict__ vv,
                                              __bf16* __restrict__ ao) {
    __shared__ __align__(16) __bf16 P[4][16][72];

    const int lane = threadIdx.x & 63, wv = threadIdx.x >> 6;
    const int g = lane >> 4, c16 = lane & 15;
    const int bh = blockIdx.y;
    const int b = bh >> 3, h = bh & 7;
    const int i0 = blockIdx.x * 64 + wv * 16;

    const __bf16* qbase = qt + ((size_t)bh * NT + i0) * HD;
    const __bf16* kbase = kt + (size_t)bh * NT * HD;
    const __bf16* vbase = vv + (size_t)bh * HD * NT;

    const bf16x8 aq = *(const bf16x8_ma*)(qbase + (size_t)c16 * HD + g * 8);

    f32x4 oacc[2];
    oacc[0] = zero4(); oacc[1] = zero4();
    float mi[4], li[4];
#pragma unroll
    for (int r = 0; r < 4; ++r) { mi[r] = -1e30f; li[r] = 0.f; }

    for (int j0 = 0; j0 < NT; j0 += 64) {
        f32x4 s[4];
#pragma unroll
        for (int js = 0; js < 4; ++js) {
            bf16x8 bk = *(const bf16x8_ma*)(kbase + (size_t)(j0 + js * 16 + c16) * HD + g * 8);
            s[js] = __builtin_amdgcn_mfma_f32_16x16x32_bf16(aq, bk, zero4(), 0, 0, 0);
        }
        float mx[4];
#pragma unroll
        for (int r = 0; r < 4; ++r)
            mx[r] = fmaxf(fmaxf(s[0][r], s[1][r]), fmaxf(s[2][r], s[3][r]));
#pragma unroll
        for (int mask = 1; mask <= 8; mask <<= 1)
#pragma unroll
            for (int r = 0; r < 4; ++r)
                mx[r] = fmaxf(mx[r], __shfl_xor(mx[r], mask, 64));

        float al[4], rs[4];
#pragma unroll
        for (int r = 0; r < 4; ++r) {
            float mn = fmaxf(mi[r], mx[r]);
            al[r] = __expf(mi[r] - mn);
            mi[r] = mn;
            rs[r] = 0.f;
        }
#pragma unroll
        for (int js = 0; js < 4; ++js)
#pragma unroll
            for (int r = 0; r < 4; ++r) {
                float p = __expf(s[js][r] - mi[r]);
                rs[r] += p;
                P[wv][g * 4 + r][js * 16 + c16] = (__bf16)p;
            }
#pragma unroll
        for (int mask = 1; mask <= 8; mask <<= 1)
#pragma unroll
            for (int r = 0; r < 4; ++r)
                rs[r] += __shfl_xor(rs[r], mask, 64);
#pragma unroll
        for (int r = 0; r < 4; ++r) li[r] = li[r] * al[r] + rs[r];
#pragma unroll
        for (int t = 0; t < 2; ++t)
#pragma unroll
            for (int r = 0; r < 4; ++r) oacc[t][r] *= al[r];
#pragma unroll
        for (int ks = 0; ks < 2; ++ks) {
            bf16x8 ap = *(const bf16x8_ma*)(&P[wv][c16][ks * 32 + g * 8]);
#pragma unroll
            for (int t = 0; t < 2; ++t) {
                bf16x8 bv = *(const bf16x8_ma*)(vbase + (size_t)(t * 16 + c16) * NT + j0 + ks * 32 + g * 8);
                oacc[t] = __builtin_amdgcn_mfma_f32_16x16x32_bf16(ap, bv, oacc[t], 0, 0, 0);
            }
        }
    }

    // ao [b][tok][c], c = h*32 + t*16 + c16
#pragma unroll
    for (int t = 0; t < 2; ++t)
#pragma unroll
        for (int r = 0; r < 4; ++r) {
            const int tok = i0 + g * 4 + r;
            ao[((size_t)(b * NT) + tok) * CC + h * HD + t * 16 + c16] =
                (__bf16)(oacc[t][r] / li[r]);
        }
}

// ---------------------------------------------------------------------------
// Kernel 4: cooperative in-place proj + residual, F32 OUTPUT.
// ao lives in d_out's upper half (bf16); out overwrites all of d_out (f32).
// 256 blocks x 256 threads; stage own 32 ao rows -> grid.sync -> write.
//   out[b][o][t] = sum_c wp[o][c] * ao[b][t][c] + x[b][o][t]
// ---------------------------------------------------------------------------
__global__ __launch_bounds__(256) void proj_coop(const float* __restrict__ wp,
                                                 const float* __restrict__ x,
                                                 const __bf16* __restrict__ ao,
                                                 float* __restrict__ out) {
    __shared__ __bf16 aols[32][CC];  // 16 KB

    const int tid = threadIdx.x;
    const int gt0 = blockIdx.x * 32;   // global token base (b*4096 + tok)

    for (int e = tid; e < 32 * CC; e += 256) {
        const int tl = e >> 8, c = e & 255;
        aols[tl][c] = ao[(size_t)(gt0 + tl) * CC + c];
    }
    __syncthreads();
    cg::this_grid().sync();   // ALL ao reads complete before ANY f32 write

    const int o = tid;
    float s[32];
#pragma unroll
    for (int tl = 0; tl < 32; ++tl) s[tl] = 0.f;
    const float* wrow = wp + (size_t)o * CC;
    for (int c = 0; c < CC; ++c) {
        const float wv = wrow[c];
#pragma unroll
        for (int tl = 0; tl < 32; ++tl)
            s[tl] += wv * (float)aols[tl][c];
    }
#pragma unroll
    for (int tl = 0; tl < 32; ++tl) {
        const int gt  = gt0 + tl;
        const int b   = gt >> 12, t = gt & 4095;
        const size_t idx = ((size_t)(b * CC + o)) * NT + t;
        out[idx] = s[tl] + x[idx];            // f32 store
    }
}

// ---------------------------------------------------------------------------
extern "C" void kernel_launch(void* const* d_in, const int* in_sizes, int n_in,
                              void* d_out, int out_size, void* d_ws, size_t ws_size,
                              hipStream_t stream) {
    const int SX  = NB * CC * NT;   // 2,097,152
    const int SW3 = 3 * CC * CC;    //   196,608
    const int SW1 = CC * CC;        //    65,536
    const size_t E = (size_t)SX;

    // Identify inputs by element count (hedged x1/x2/x4).
    const float* x  = nullptr;
    const float* wq = nullptr;
    const float* wp = nullptr;
    for (int i = 0; i < n_in; ++i) {
        const int sz = in_sizes[i];
        if (sz == SX || sz == 2 * SX || sz == 4 * SX)           x  = (const float*)d_in[i];
        else if (sz == SW3 || sz == 2 * SW3 || sz == 4 * SW3)   wq = (const float*)d_in[i];
        else if (sz == SW1 || sz == 2 * SW1 || sz == 4 * SW1)   wp = (const float*)d_in[i];
    }
    if (!x || !wq || !wp) {
        x  = (const float*)d_in[0];
        wq = (const float*)d_in[1];
        wp = (const float*)d_in[2];
    }

    // Workspace layout (bf16), total 16.4 MB (R5==R6 proved <=16.8MB safe):
    __bf16* ws  = (__bf16*)d_ws;
    __bf16* wqb = ws;                  // 196,608
    __bf16* xt  = ws + SW3;            // 2M
    __bf16* qt  = xt + E;              // 2M
    __bf16* kt  = qt + E;              // 2M
    __bf16* vv  = kt + E;              // 2M

    float*  out = (float*)d_out;
    __bf16* ao  = (__bf16*)d_out + E;  // upper 4MB of d_out holds ao (bf16)

    convw_k<<<dim3(SW3 / 256), 256, 0, stream>>>(wq, wqb, SW3);
    transpose_k<<<dim3(NT / 16, NB), 256, 0, stream>>>(x, xt);
    qkv_k<<<dim3(NT / 64, (3 * CC) / 64, NB), 256, 0, stream>>>(wqb, xt, qt, kt, vv);
    attn_k<<<dim3(NT / 64, NB * NHD), 256, 0, stream>>>(qt, kt, vv, ao);

    void* args[] = { (void*)&wp, (void*)&x, (void*)&ao, (void*)&out };
    hipLaunchCooperativeKernel((void*)proj_coop, dim3(256), dim3(256),
                               args, 0, stream);
}

// Round 14
// 288.292 us; speedup vs baseline: 1.3355x; 1.3355x over previous
//
#include <hip/hip_runtime.h>
#include <hip/hip_bf16.h>

// Problem constants
#define NB  2      // batch
#define CC  256    // channels
#define NHD 8      // heads
#define HD  32     // head dim
#define NT  4096   // tokens = H*W

typedef __bf16 bf16x8 __attribute__((ext_vector_type(8)));
typedef bf16x8 bf16x8_ma __attribute__((may_alias));
typedef float  f32x4  __attribute__((ext_vector_type(4)));

static __device__ __forceinline__ f32x4 zero4() {
    f32x4 z = {0.f, 0.f, 0.f, 0.f}; return z;
}

// ---------------------------------------------------------------------------
// ROUND 14: first optimization pass on the R13 PASS (385 us).
//  1. attn_k: FIXED-MAX softmax (m=0; |s|<~7 so exp can't overflow f32),
//     deferred l-reduction -> removes 32 shfls + rescale chain per j-tile.
//  2. proj: cooperative scalar-LDS GEMM -> MFMA GEMM (qkv_k pattern), f32 out.
//     ao lives in ws, REUSING xt's region (dead after qkv_k; stream-ordered).
//  3. wp converted to bf16 like wq.
// ws layout (bf16 elems): wqb[196608] wpb[65536] xt/ao[2M] qt[2M] kt[2M] vv[2M]
//   = 16.5 MB (<= R13's proven footprint + 0.13 MB).
// ---------------------------------------------------------------------------

// ---------------------------------------------------------------------------
// Kernel 0: f32 -> bf16 convert (weights).
// ---------------------------------------------------------------------------
__global__ __launch_bounds__(256) void convw_k(const float* __restrict__ src,
                                               __bf16* __restrict__ dst, int n) {
    const int i = blockIdx.x * 256 + threadIdx.x;
    if (i < n) dst[i] = (__bf16)src[i];
}

// ---------------------------------------------------------------------------
// Kernel 1: transpose+convert x f32 [b][c][n] -> xt bf16 [b][n][c].
// ---------------------------------------------------------------------------
__global__ __launch_bounds__(256) void transpose_k(const float* __restrict__ x,
                                                   __bf16* __restrict__ xt) {
    const int c  = threadIdx.x;
    const int b  = blockIdx.y;
    const int n0 = blockIdx.x * 16;
    const float* xp = x  + ((size_t)(b * CC + c)) * NT + n0;
    __bf16*      op = xt + ((size_t)(b * NT + n0)) * CC + c;
#pragma unroll
    for (int i = 0; i < 16; ++i) op[i * CC] = (__bf16)xp[i];
}

// ---------------------------------------------------------------------------
// Kernel 2: QKV GEMM (MFMA, validated R13).
// qt/kt token-major [bh][n][32] (q scaled 1/sqrt(32)), vv d-major [bh][32][n].
// grid (NT/64, 768/64, NB), block 256.
// ---------------------------------------------------------------------------
__global__ __launch_bounds__(256) void qkv_k(const __bf16* __restrict__ wqkv,
                                             const __bf16* __restrict__ xt,
                                             __bf16* __restrict__ qt,
                                             __bf16* __restrict__ kt,
                                             __bf16* __restrict__ vv) {
    const int lane = threadIdx.x & 63, wv = threadIdx.x >> 6;
    const int g = lane >> 4, c16 = lane & 15;
    const int b    = blockIdx.z;
    const int o0   = blockIdx.y * 64 + wv * 16;
    const int tok0 = blockIdx.x * 64;

    const __bf16* arow = wqkv + (size_t)(o0 + c16) * CC + g * 8;
    const __bf16* brow = xt + ((size_t)(b * NT + tok0 + c16)) * CC + g * 8;

    f32x4 acc[4];
#pragma unroll
    for (int i = 0; i < 4; ++i) acc[i] = zero4();

#pragma unroll
    for (int k0 = 0; k0 < CC; k0 += 32) {
        bf16x8 a = *(const bf16x8_ma*)(arow + k0);
#pragma unroll
        for (int js = 0; js < 4; ++js) {
            bf16x8 bb = *(const bf16x8_ma*)(brow + (size_t)js * 16 * CC + k0);
            acc[js] = __builtin_amdgcn_mfma_f32_16x16x32_bf16(a, bb, acc[js], 0, 0, 0);
        }
    }

#pragma unroll
    for (int js = 0; js < 4; ++js) {
        const int tok = tok0 + js * 16 + c16;
#pragma unroll
        for (int r = 0; r < 4; ++r) {
            const int o   = o0 + g * 4 + r;
            const float v = acc[js][r];
            const int reg = o >> 8;        // 0=q, 1=k, 2=v (wave-uniform)
            const int oo  = o & 255;
            const int h = oo >> 5, dd = oo & 31;
            const size_t bh = (size_t)(b * NHD + h);
            if (reg == 0)      qt[(bh * NT + tok) * HD + dd] = (__bf16)(v * 0.17677669529663687f);
            else if (reg == 1) kt[(bh * NT + tok) * HD + dd] = (__bf16)v;
            else               vv[(bh * HD + dd) * NT + tok] = (__bf16)v;
        }
    }
}

// ---------------------------------------------------------------------------
// Kernel 3: MFMA flash attention, FIXED-MAX softmax (m=0, deferred l).
// block = (b,h) x 64-query tile; wave owns 16 rows; d=32 = one MFMA K.
// Per j-tile: 4 score MFMAs -> p=exp(s) -> P to per-wave LDS -> 4 PV MFMAs.
// No online max/rescale: scores bounded (|s| <~ 7), exp can't overflow f32.
// l accumulated per-lane, reduced once at the end. ao -> [b][t][c] (bf16).
// grid (NT/64, NB*NHD), block 256.
// ---------------------------------------------------------------------------
__global__ __launch_bounds__(256) void attn_k(const __bf16* __restrict__ qt,
                                              const __bf16* __restrict__ kt,
                                              const __bf16* __restrict__ vv,
                                              __bf16* __restrict__ ao) {
    __shared__ __align__(16) __bf16 P[4][16][72];

    const int lane = threadIdx.x & 63, wv = threadIdx.x >> 6;
    const int g = lane >> 4, c16 = lane & 15;
    const int bh = blockIdx.y;
    const int b = bh >> 3, h = bh & 7;
    const int i0 = blockIdx.x * 64 + wv * 16;

    const __bf16* qbase = qt + ((size_t)bh * NT + i0) * HD;
    const __bf16* kbase = kt + (size_t)bh * NT * HD;
    const __bf16* vbase = vv + (size_t)bh * HD * NT;

    const bf16x8 aq = *(const bf16x8_ma*)(qbase + (size_t)c16 * HD + g * 8);

    f32x4 oacc[2];
    oacc[0] = zero4(); oacc[1] = zero4();
    float rs[4] = {0.f, 0.f, 0.f, 0.f};

    for (int j0 = 0; j0 < NT; j0 += 64) {
        // ---- scores: 4 sub-tiles of 16 cols ----
        f32x4 s[4];
#pragma unroll
        for (int js = 0; js < 4; ++js) {
            bf16x8 bk = *(const bf16x8_ma*)(kbase + (size_t)(j0 + js * 16 + c16) * HD + g * 8);
            s[js] = __builtin_amdgcn_mfma_f32_16x16x32_bf16(aq, bk, zero4(), 0, 0, 0);
        }
        // ---- p = exp(s); accumulate per-lane l; store P (A-feed layout) ----
#pragma unroll
        for (int js = 0; js < 4; ++js)
#pragma unroll
            for (int r = 0; r < 4; ++r) {
                const float p = __expf(s[js][r]);
                rs[r] += p;
                P[wv][g * 4 + r][js * 16 + c16] = (__bf16)p;
            }
        // ---- PV: O[i][dd] += P[i][j] * V[dd][j] ----
#pragma unroll
        for (int ks = 0; ks < 2; ++ks) {
            bf16x8 ap = *(const bf16x8_ma*)(&P[wv][c16][ks * 32 + g * 8]);
#pragma unroll
            for (int t = 0; t < 2; ++t) {
                bf16x8 bv = *(const bf16x8_ma*)(vbase + (size_t)(t * 16 + c16) * NT + j0 + ks * 32 + g * 8);
                oacc[t] = __builtin_amdgcn_mfma_f32_16x16x32_bf16(ap, bv, oacc[t], 0, 0, 0);
            }
        }
    }

    // ---- one-time l reduction across the 16 lanes of group g ----
#pragma unroll
    for (int mask = 1; mask <= 8; mask <<= 1)
#pragma unroll
        for (int r = 0; r < 4; ++r)
            rs[r] += __shfl_xor(rs[r], mask, 64);

    // ---- ao [b][tok][c], c = h*32 + t*16 + c16 ----
#pragma unroll
    for (int t = 0; t < 2; ++t)
#pragma unroll
        for (int r = 0; r < 4; ++r) {
            const int tok = i0 + g * 4 + r;
            ao[((size_t)(b * NT) + tok) * CC + h * HD + t * 16 + c16] =
                (__bf16)(oacc[t][r] / rs[r]);
        }
}

// ---------------------------------------------------------------------------
// Kernel 4: proj GEMM + residual (MFMA, qkv_k pattern), F32 output.
//   out[b][o][tok] = sum_c wp[o][c] * ao[b][tok][c] + x[b][o][tok]
// grid (NT/64, CC/64, NB), block 256.
// ---------------------------------------------------------------------------
__global__ __launch_bounds__(256) void proj_k(const __bf16* __restrict__ wp,
                                              const __bf16* __restrict__ ao,
                                              const float* __restrict__ x,
                                              float* __restrict__ out) {
    const int lane = threadIdx.x & 63, wv = threadIdx.x >> 6;
    const int g = lane >> 4, c16 = lane & 15;
    const int b    = blockIdx.z;
    const int o0   = blockIdx.y * 64 + wv * 16;
    const int tok0 = blockIdx.x * 64;

    const __bf16* arow = wp + (size_t)(o0 + c16) * CC + g * 8;
    const __bf16* brow = ao + ((size_t)(b * NT + tok0 + c16)) * CC + g * 8;

    f32x4 acc[4];
#pragma unroll
    for (int i = 0; i < 4; ++i) acc[i] = zero4();

#pragma unroll
    for (int k0 = 0; k0 < CC; k0 += 32) {
        bf16x8 a = *(const bf16x8_ma*)(arow + k0);
#pragma unroll
        for (int js = 0; js < 4; ++js) {
            bf16x8 bb = *(const bf16x8_ma*)(brow + (size_t)js * 16 * CC + k0);
            acc[js] = __builtin_amdgcn_mfma_f32_16x16x32_bf16(a, bb, acc[js], 0, 0, 0);
        }
    }

#pragma unroll
    for (int js = 0; js < 4; ++js) {
        const int tok = tok0 + js * 16 + c16;
#pragma unroll
        for (int r = 0; r < 4; ++r) {
            const int o = o0 + g * 4 + r;
            const size_t idx = ((size_t)(b * CC + o)) * NT + tok;
            out[idx] = acc[js][r] + x[idx];   // f32 store, coalesced over c16
        }
    }
}

// ---------------------------------------------------------------------------
extern "C" void kernel_launch(void* const* d_in, const int* in_sizes, int n_in,
                              void* d_out, int out_size, void* d_ws, size_t ws_size,
                              hipStream_t stream) {
    const int SX  = NB * CC * NT;   // 2,097,152
    const int SW3 = 3 * CC * CC;    //   196,608
    const int SW1 = CC * CC;        //    65,536
    const size_t E = (size_t)SX;

    // Identify inputs by element count (hedged x1/x2/x4).
    const float* x  = nullptr;
    const float* wq = nullptr;
    const float* wp = nullptr;
    for (int i = 0; i < n_in; ++i) {
        const int sz = in_sizes[i];
        if (sz == SX || sz == 2 * SX || sz == 4 * SX)           x  = (const float*)d_in[i];
        else if (sz == SW3 || sz == 2 * SW3 || sz == 4 * SW3)   wq = (const float*)d_in[i];
        else if (sz == SW1 || sz == 2 * SW1 || sz == 4 * SW1)   wp = (const float*)d_in[i];
    }
    if (!x || !wq || !wp) {
        x  = (const float*)d_in[0];
        wq = (const float*)d_in[1];
        wp = (const float*)d_in[2];
    }

    // Workspace (bf16 elements), 16.5 MB total:
    __bf16* ws  = (__bf16*)d_ws;
    __bf16* wqb = ws;                    // 196,608
    __bf16* wpb = wqb + SW3;             //  65,536
    __bf16* xt  = wpb + SW1;             // 2M  (becomes ao after qkv_k)
    __bf16* qt  = xt + E;                // 2M
    __bf16* kt  = qt + E;                // 2M
    __bf16* vv  = kt + E;                // 2M
    __bf16* ao  = xt;                    // reuse: xt dead after qkv_k

    float* out = (float*)d_out;

    convw_k<<<dim3(SW3 / 256), 256, 0, stream>>>(wq, wqb, SW3);
    convw_k<<<dim3(SW1 / 256), 256, 0, stream>>>(wp, wpb, SW1);
    transpose_k<<<dim3(NT / 16, NB), 256, 0, stream>>>(x, xt);
    qkv_k<<<dim3(NT / 64, (3 * CC) / 64, NB), 256, 0, stream>>>(wqb, xt, qt, kt, vv);
    attn_k<<<dim3(NT / 64, NB * NHD), 256, 0, stream>>>(qt, kt, vv, ao);
    proj_k<<<dim3(NT / 64, CC / 64, NB), 256, 0, stream>>>(wpb, ao, x, out);
}

// Round 15
// 285.368 us; speedup vs baseline: 1.3492x; 1.0102x over previous
//
#include <hip/hip_runtime.h>
#include <hip/hip_bf16.h>

// Problem constants
#define NB  2      // batch
#define CC  256    // channels
#define NHD 8      // heads
#define HD  32     // head dim
#define NT  4096   // tokens = H*W

typedef __bf16 bf16x8 __attribute__((ext_vector_type(8)));
typedef bf16x8 bf16x8_ma __attribute__((may_alias));
typedef float  f32x4  __attribute__((ext_vector_type(4)));

static __device__ __forceinline__ f32x4 zero4() {
    f32x4 z = {0.f, 0.f, 0.f, 0.f}; return z;
}

// q pre-scale: log2(e) / sqrt(32)  (exp(s) == exp2(s * log2 e))
#define QSCALE 0.25505392421795654f

// ---------------------------------------------------------------------------
// ROUND 15: attack attn_k's latency-boundedness (R14: MfmaUtil 7.5, VALU 27,
// HBM 2.7, Occupancy 45% -- all pipes idle; grid caps waves at 16/CU).
//  1. j-split flash-decoding: 8-wave blocks (4 query-tiles x 2 j-segments),
//     additive (O,l) combine in LDS (fixed-max softmax => no rescale).
//     32 waves/CU = 100% occupancy, per-wave chain halved.
//  2. exp2f + q pre-scaled by log2e/sqrt(d): kills 16 v_mul/iter/lane.
//  3. P row stride 72 -> 76 (breaks g=0/g=2 LDS bank collision).
//  4. LDS-tiled transpose (old one uncoalesced both sides).
// ---------------------------------------------------------------------------

// ---------------------------------------------------------------------------
// Kernel 0: f32 -> bf16 convert (weights).
// ---------------------------------------------------------------------------
__global__ __launch_bounds__(256) void convw_k(const float* __restrict__ src,
                                               __bf16* __restrict__ dst, int n) {
    const int i = blockIdx.x * 256 + threadIdx.x;
    if (i < n) dst[i] = (__bf16)src[i];
}

// ---------------------------------------------------------------------------
// Kernel 1: LDS-tiled transpose+convert x f32 [b][c][n] -> xt bf16 [b][n][c].
// 64x64 tiles; both global phases coalesced. grid (NT/64, CC/64, NB) x 256.
// ---------------------------------------------------------------------------
__global__ __launch_bounds__(256) void transpose_k(const float* __restrict__ x,
                                                   __bf16* __restrict__ xt) {
    __shared__ __bf16 T[64][65];
    const int tid = threadIdx.x;
    const int n0 = blockIdx.x * 64, c0 = blockIdx.y * 64, b = blockIdx.z;

#pragma unroll
    for (int rep = 0; rep < 16; ++rep) {
        const int e = rep * 256 + tid;
        const int cl = e >> 6, nl = e & 63;          // consecutive tid -> n
        T[nl][cl] = (__bf16)x[((size_t)(b * CC + c0 + cl)) * NT + n0 + nl];
    }
    __syncthreads();
#pragma unroll
    for (int rep = 0; rep < 16; ++rep) {
        const int e = rep * 256 + tid;
        const int nl = e >> 6, cl = e & 63;          // consecutive tid -> c
        xt[((size_t)(b * NT + n0 + nl)) * CC + c0 + cl] = T[nl][cl];
    }
}

// ---------------------------------------------------------------------------
// Kernel 2: QKV GEMM (MFMA). q pre-scaled by QSCALE (log2e/sqrt(d)).
// qt/kt token-major [bh][n][32], vv d-major [bh][32][n].
// grid (NT/64, 768/64, NB), block 256.
// ---------------------------------------------------------------------------
__global__ __launch_bounds__(256) void qkv_k(const __bf16* __restrict__ wqkv,
                                             const __bf16* __restrict__ xt,
                                             __bf16* __restrict__ qt,
                                             __bf16* __restrict__ kt,
                                             __bf16* __restrict__ vv) {
    const int lane = threadIdx.x & 63, wv = threadIdx.x >> 6;
    const int g = lane >> 4, c16 = lane & 15;
    const int b    = blockIdx.z;
    const int o0   = blockIdx.y * 64 + wv * 16;
    const int tok0 = blockIdx.x * 64;

    const __bf16* arow = wqkv + (size_t)(o0 + c16) * CC + g * 8;
    const __bf16* brow = xt + ((size_t)(b * NT + tok0 + c16)) * CC + g * 8;

    f32x4 acc[4];
#pragma unroll
    for (int i = 0; i < 4; ++i) acc[i] = zero4();

#pragma unroll
    for (int k0 = 0; k0 < CC; k0 += 32) {
        bf16x8 a = *(const bf16x8_ma*)(arow + k0);
#pragma unroll
        for (int js = 0; js < 4; ++js) {
            bf16x8 bb = *(const bf16x8_ma*)(brow + (size_t)js * 16 * CC + k0);
            acc[js] = __builtin_amdgcn_mfma_f32_16x16x32_bf16(a, bb, acc[js], 0, 0, 0);
        }
    }

#pragma unroll
    for (int js = 0; js < 4; ++js) {
        const int tok = tok0 + js * 16 + c16;
#pragma unroll
        for (int r = 0; r < 4; ++r) {
            const int o   = o0 + g * 4 + r;
            const float v = acc[js][r];
            const int reg = o >> 8;        // 0=q, 1=k, 2=v (wave-uniform)
            const int oo  = o & 255;
            const int h = oo >> 5, dd = oo & 31;
            const size_t bh = (size_t)(b * NHD + h);
            if (reg == 0)      qt[(bh * NT + tok) * HD + dd] = (__bf16)(v * QSCALE);
            else if (reg == 1) kt[(bh * NT + tok) * HD + dd] = (__bf16)v;
            else               vv[(bh * HD + dd) * NT + tok] = (__bf16)v;
        }
    }
}

// ---------------------------------------------------------------------------
// Kernel 3: MFMA flash attention, fixed-max softmax + j-split decoding.
// block = 512 threads = 8 waves: wave wv -> query-tile qp = wv&3 (16 rows),
// j-segment seg = wv>>2 (2048 tokens). Additive combine via LDS at the end.
// grid (NT/64, NB*NHD), block 512.
// ---------------------------------------------------------------------------
__global__ __launch_bounds__(512) void attn_k(const __bf16* __restrict__ qt,
                                              const __bf16* __restrict__ kt,
                                              const __bf16* __restrict__ vv,
                                              __bf16* __restrict__ ao) {
    __shared__ __align__(16) __bf16 P[8][16][76];   // 19.0 KB
    __shared__ float Olds[4][16][33];               //  8.25 KB (seg-1 partials)
    __shared__ float llds[4][16];                   //  0.25 KB

    const int tid  = threadIdx.x;
    const int lane = tid & 63, wv = tid >> 6;       // wv 0..7
    const int qp = wv & 3, seg = wv >> 2;
    const int g = lane >> 4, c16 = lane & 15;
    const int bh = blockIdx.y;
    const int b = bh >> 3, h = bh & 7;
    const int i0 = blockIdx.x * 64 + qp * 16;

    const __bf16* qbase = qt + ((size_t)bh * NT + i0) * HD;
    const __bf16* kbase = kt + (size_t)bh * NT * HD;
    const __bf16* vbase = vv + (size_t)bh * HD * NT;

    const bf16x8 aq = *(const bf16x8_ma*)(qbase + (size_t)c16 * HD + g * 8);

    f32x4 oacc[2];
    oacc[0] = zero4(); oacc[1] = zero4();
    float rs[4] = {0.f, 0.f, 0.f, 0.f};

    const int j_begin = seg * (NT / 2);
    const int j_end   = j_begin + (NT / 2);

    for (int j0 = j_begin; j0 < j_end; j0 += 64) {
        // ---- scores: 4 sub-tiles of 16 cols ----
        f32x4 s[4];
#pragma unroll
        for (int js = 0; js < 4; ++js) {
            bf16x8 bk = *(const bf16x8_ma*)(kbase + (size_t)(j0 + js * 16 + c16) * HD + g * 8);
            s[js] = __builtin_amdgcn_mfma_f32_16x16x32_bf16(aq, bk, zero4(), 0, 0, 0);
        }
        // ---- p = exp2(s) (q pre-scaled by log2e); accumulate l; store P ----
#pragma unroll
        for (int js = 0; js < 4; ++js)
#pragma unroll
            for (int r = 0; r < 4; ++r) {
                const float p = exp2f(s[js][r]);
                rs[r] += p;
                P[wv][g * 4 + r][js * 16 + c16] = (__bf16)p;
            }
        // ---- PV: O[i][dd] += P[i][j] * V[dd][j] ----
#pragma unroll
        for (int ks = 0; ks < 2; ++ks) {
            bf16x8 ap = *(const bf16x8_ma*)(&P[wv][c16][ks * 32 + g * 8]);
#pragma unroll
            for (int t = 0; t < 2; ++t) {
                bf16x8 bv = *(const bf16x8_ma*)(vbase + (size_t)(t * 16 + c16) * NT + j0 + ks * 32 + g * 8);
                oacc[t] = __builtin_amdgcn_mfma_f32_16x16x32_bf16(ap, bv, oacc[t], 0, 0, 0);
            }
        }
    }

    // ---- l reduction across the 16 lanes of group g ----
#pragma unroll
    for (int mask = 1; mask <= 8; mask <<= 1)
#pragma unroll
        for (int r = 0; r < 4; ++r)
            rs[r] += __shfl_xor(rs[r], mask, 64);

    // ---- additive cross-segment combine via LDS ----
    if (seg == 1) {
#pragma unroll
        for (int t = 0; t < 2; ++t)
#pragma unroll
            for (int r = 0; r < 4; ++r)
                Olds[qp][g * 4 + r][t * 16 + c16] = oacc[t][r];
        if (c16 == 0)
#pragma unroll
            for (int r = 0; r < 4; ++r)
                llds[qp][g * 4 + r] = rs[r];
    }
    __syncthreads();
    if (seg == 0) {
        float lf[4];
#pragma unroll
        for (int r = 0; r < 4; ++r)
            lf[r] = rs[r] + llds[qp][g * 4 + r];
#pragma unroll
        for (int t = 0; t < 2; ++t)
#pragma unroll
            for (int r = 0; r < 4; ++r) {
                const int tok = i0 + g * 4 + r;
                const float v = oacc[t][r] + Olds[qp][g * 4 + r][t * 16 + c16];
                ao[((size_t)(b * NT) + tok) * CC + h * HD + t * 16 + c16] =
                    (__bf16)(v / lf[r]);
            }
    }
}

// ---------------------------------------------------------------------------
// Kernel 4: proj GEMM + residual (MFMA), F32 output.
//   out[b][o][tok] = sum_c wp[o][c] * ao[b][tok][c] + x[b][o][tok]
// grid (NT/64, CC/64, NB), block 256.
// ---------------------------------------------------------------------------
__global__ __launch_bounds__(256) void proj_k(const __bf16* __restrict__ wp,
                                              const __bf16* __restrict__ ao,
                                              const float* __restrict__ x,
                                              float* __restrict__ out) {
    const int lane = threadIdx.x & 63, wv = threadIdx.x >> 6;
    const int g = lane >> 4, c16 = lane & 15;
    const int b    = blockIdx.z;
    const int o0   = blockIdx.y * 64 + wv * 16;
    const int tok0 = blockIdx.x * 64;

    const __bf16* arow = wp + (size_t)(o0 + c16) * CC + g * 8;
    const __bf16* brow = ao + ((size_t)(b * NT + tok0 + c16)) * CC + g * 8;

    f32x4 acc[4];
#pragma unroll
    for (int i = 0; i < 4; ++i) acc[i] = zero4();

#pragma unroll
    for (int k0 = 0; k0 < CC; k0 += 32) {
        bf16x8 a = *(const bf16x8_ma*)(arow + k0);
#pragma unroll
        for (int js = 0; js < 4; ++js) {
            bf16x8 bb = *(const bf16x8_ma*)(brow + (size_t)js * 16 * CC + k0);
            acc[js] = __builtin_amdgcn_mfma_f32_16x16x32_bf16(a, bb, acc[js], 0, 0, 0);
        }
    }

#pragma unroll
    for (int js = 0; js < 4; ++js) {
        const int tok = tok0 + js * 16 + c16;
#pragma unroll
        for (int r = 0; r < 4; ++r) {
            const int o = o0 + g * 4 + r;
            const size_t idx = ((size_t)(b * CC + o)) * NT + tok;
            out[idx] = acc[js][r] + x[idx];   // f32 store, coalesced over c16
        }
    }
}

// ---------------------------------------------------------------------------
extern "C" void kernel_launch(void* const* d_in, const int* in_sizes, int n_in,
                              void* d_out, int out_size, void* d_ws, size_t ws_size,
                              hipStream_t stream) {
    const int SX  = NB * CC * NT;   // 2,097,152
    const int SW3 = 3 * CC * CC;    //   196,608
    const int SW1 = CC * CC;        //    65,536
    const size_t E = (size_t)SX;

    // Identify inputs by element count (hedged x1/x2/x4).
    const float* x  = nullptr;
    const float* wq = nullptr;
    const float* wp = nullptr;
    for (int i = 0; i < n_in; ++i) {
        const int sz = in_sizes[i];
        if (sz == SX || sz == 2 * SX || sz == 4 * SX)           x  = (const float*)d_in[i];
        else if (sz == SW3 || sz == 2 * SW3 || sz == 4 * SW3)   wq = (const float*)d_in[i];
        else if (sz == SW1 || sz == 2 * SW1 || sz == 4 * SW1)   wp = (const float*)d_in[i];
    }
    if (!x || !wq || !wp) {
        x  = (const float*)d_in[0];
        wq = (const float*)d_in[1];
        wp = (const float*)d_in[2];
    }

    // Workspace (bf16 elements), 16.5 MB total (proven in R13/R14):
    __bf16* ws  = (__bf16*)d_ws;
    __bf16* wqb = ws;                    // 196,608
    __bf16* wpb = wqb + SW3;             //  65,536
    __bf16* xt  = wpb + SW1;             // 2M  (becomes ao after qkv_k)
    __bf16* qt  = xt + E;                // 2M
    __bf16* kt  = qt + E;                // 2M
    __bf16* vv  = kt + E;                // 2M
    __bf16* ao  = xt;                    // reuse: xt dead after qkv_k

    float* out = (float*)d_out;

    convw_k<<<dim3(SW3 / 256), 256, 0, stream>>>(wq, wqb, SW3);
    convw_k<<<dim3(SW1 / 256), 256, 0, stream>>>(wp, wpb, SW1);
    transpose_k<<<dim3(NT / 64, CC / 64, NB), 256, 0, stream>>>(x, xt);
    qkv_k<<<dim3(NT / 64, (3 * CC) / 64, NB), 256, 0, stream>>>(wqb, xt, qt, kt, vv);
    attn_k<<<dim3(NT / 64, NB * NHD), 512, 0, stream>>>(qt, kt, vv, ao);
    proj_k<<<dim3(NT / 64, CC / 64, NB), 256, 0, stream>>>(wpb, ao, x, out);
}